// Round 2
// baseline (3054.714 us; speedup 1.0000x reference)
//
#include <hip/hip_runtime.h>
#include <math.h>

namespace {
constexpr int kT = 8, kL = 8, kN = 500, kD = 64, kK = 12;
constexpr int kLN  = kL * kN;        // 4000
constexpr int kTLN = kT * kL * kN;   // 32000
constexpr int kBUF = kTLN * kD;      // 2,048,000 floats
}

__device__ __forceinline__ float sigf(float v) { return 1.f / (1.f + __expf(-v)); }

// Evolution step. Lane = output column. w1 column in 128 VGPRs (preloaded once
// per wave, reused over 8 rows). x-row reads are wave-uniform -> s_load.
__global__ void evo_kernel(const float* __restrict__ st, const float* __restrict__ th,
                           const float* __restrict__ prev, float* __restrict__ cur,
                           float* __restrict__ diff, const float* __restrict__ w1) {
    int lane = threadIdx.x & 63;
    int wave = __builtin_amdgcn_readfirstlane(threadIdx.x >> 6);
    float w[128];
#pragma unroll
    for (int j = 0; j < 128; ++j) w[j] = w1[j * kD + lane];
    int wid = blockIdx.x * 4 + wave;           // 0..499
#pragma unroll 1
    for (int r = 0; r < 8; ++r) {
        int row = wid * 8 + r;                 // 0..3999
        const float4* xn4 = reinterpret_cast<const float4*>(prev) + row * 16;
        const float4* xs4 = reinterpret_cast<const float4*>(st) + row * 16;
        float t = th[row];
        float acc = 0.f;
#pragma unroll
        for (int jj = 0; jj < 16; ++jj) {
            float4 a = xn4[jj];
            acc = fmaf(a.x, w[4 * jj + 0], acc);
            acc = fmaf(a.y, w[4 * jj + 1], acc);
            acc = fmaf(a.z, w[4 * jj + 2], acc);
            acc = fmaf(a.w, w[4 * jj + 3], acc);
        }
#pragma unroll
        for (int jj = 0; jj < 16; ++jj) {
            float4 a = xs4[jj];
            acc = fmaf(a.x, w[64 + 4 * jj + 0], acc);
            acc = fmaf(a.y, w[64 + 4 * jj + 1], acc);
            acc = fmaf(a.z, w[64 + 4 * jj + 2], acc);
            acc = fmaf(a.w, w[64 + 4 * jj + 3], acc);
        }
        float xn = prev[(size_t)row * kD + lane];
        float nv = sigf(acc * t + xn * (1.f - t));
        cur[(size_t)row * kD + lane]  = nv;
        diff[(size_t)row * kD + lane] = nv - xn;
    }
}

// Q = X@wq, XK = X@wk in one pass over X. Lane = column; both weight columns
// in 128 VGPRs; x-rows via wave-uniform (scalar) loads. 16 rows per wave.
__global__ void gemm_qk(const float* __restrict__ X, const float* __restrict__ wq,
                        const float* __restrict__ wk, float* __restrict__ Q,
                        float* __restrict__ XK) {
    int lane = threadIdx.x & 63;
    int wave = __builtin_amdgcn_readfirstlane(threadIdx.x >> 6);
    float wqj[64], wkj[64];
#pragma unroll
    for (int j = 0; j < 64; ++j) {
        wqj[j] = wq[j * 64 + lane];
        wkj[j] = wk[j * 64 + lane];
    }
    int wid = blockIdx.x * 4 + wave;           // 0..1999
#pragma unroll 1
    for (int r = 0; r < 16; ++r) {
        int row = wid * 16 + r;                // 0..31999
        const float4* xr = reinterpret_cast<const float4*>(X) + row * 16;
        float aq = 0.f, ak = 0.f;
#pragma unroll
        for (int jj = 0; jj < 16; ++jj) {
            float4 xv = xr[jj];
            aq = fmaf(xv.x, wqj[4 * jj + 0], aq); ak = fmaf(xv.x, wkj[4 * jj + 0], ak);
            aq = fmaf(xv.y, wqj[4 * jj + 1], aq); ak = fmaf(xv.y, wkj[4 * jj + 1], ak);
            aq = fmaf(xv.z, wqj[4 * jj + 2], aq); ak = fmaf(xv.z, wkj[4 * jj + 2], ak);
            aq = fmaf(xv.w, wqj[4 * jj + 3], aq); ak = fmaf(xv.w, wkj[4 * jj + 3], ak);
        }
        Q[(size_t)row * 64 + lane]  = aq;
        XK[(size_t)row * 64 + lane] = ak;
    }
}

// Scores + softmax + combine. Quarter-wave layout: 4 rows per wave, 16 lanes
// per row, float4 (4 d-values) per lane. Butterfly only 4 stages (width 16).
// O[row] = Q[row] + sum_j a_j * XK[neigh_j]. O may alias Q (row-local).
__global__ void score_kernel(const float* __restrict__ Q, const float* __restrict__ XK,
                             const int* __restrict__ neigh, float* __restrict__ O) {
    int lane = threadIdx.x & 63;
    int wave = threadIdx.x >> 6;
    int sub  = lane >> 4;                      // row within wave
    int g    = lane & 15;                      // d-group (4 floats)
    int row  = blockIdx.x * 16 + wave * 4 + sub;
    int n    = row % kN;
    int slab = row - n;
    float4 q = *(reinterpret_cast<const float4*>(Q) + (size_t)row * 16 + g);
    const int4* nbp = reinterpret_cast<const int4*>(neigh + n * kK);
    int4 nb0 = nbp[0], nb1 = nbp[1], nb2 = nbp[2];
    int nb[12] = {nb0.x, nb0.y, nb0.z, nb0.w, nb1.x, nb1.y, nb1.z, nb1.w,
                  nb2.x, nb2.y, nb2.z, nb2.w};
    float4 kv[12];
    float sc[12];
#pragma unroll
    for (int j = 0; j < 12; ++j) {
        kv[j] = *(reinterpret_cast<const float4*>(XK) + (size_t)(slab + nb[j]) * 16 + g);
        sc[j] = q.x * kv[j].x + q.y * kv[j].y + q.z * kv[j].z + q.w * kv[j].w;
    }
#pragma unroll
    for (int off = 1; off < 16; off <<= 1) {
#pragma unroll
        for (int j = 0; j < 12; ++j) sc[j] += __shfl_xor(sc[j], off, 16);
    }
    float m = sc[0];
#pragma unroll
    for (int j = 1; j < 12; ++j) m = fmaxf(m, sc[j]);
    float ssum = 0.f;
#pragma unroll
    for (int j = 0; j < 12; ++j) { sc[j] = __expf(sc[j] - m); ssum += sc[j]; }
    float inv = 1.f / ssum;
    float4 o = q;
#pragma unroll
    for (int j = 0; j < 12; ++j) {
        float a = sc[j] * inv;
        o.x = fmaf(a, kv[j].x, o.x);
        o.y = fmaf(a, kv[j].y, o.y);
        o.z = fmaf(a, kv[j].z, o.z);
        o.w = fmaf(a, kv[j].w, o.w);
    }
    *(reinterpret_cast<float4*>(O) + (size_t)row * 16 + g) = o;
}

// Y = sigmoid(O@wd). If mix!=nullptr, instead accumulate mix += Y*wmix
// (init zeroes, fin applies final sigmoid). Same scalar-x GEMM structure.
__global__ void gemm_wd(const float* __restrict__ O, const float* __restrict__ wd,
                        float* __restrict__ Y, const float* __restrict__ wmix,
                        float* __restrict__ mix, int init, int fin) {
    int lane = threadIdx.x & 63;
    int wave = __builtin_amdgcn_readfirstlane(threadIdx.x >> 6);
    float wdj[64];
#pragma unroll
    for (int j = 0; j < 64; ++j) wdj[j] = wd[j * 64 + lane];
    float wm = mix ? wmix[lane] : 0.f;
    int wid = blockIdx.x * 4 + wave;           // 0..3999
#pragma unroll 1
    for (int r = 0; r < 8; ++r) {
        int row = wid * 8 + r;
        const float4* xr = reinterpret_cast<const float4*>(O) + row * 16;
        float acc = 0.f;
#pragma unroll
        for (int jj = 0; jj < 16; ++jj) {
            float4 xv = xr[jj];
            acc = fmaf(xv.x, wdj[4 * jj + 0], acc);
            acc = fmaf(xv.y, wdj[4 * jj + 1], acc);
            acc = fmaf(xv.z, wdj[4 * jj + 2], acc);
            acc = fmaf(xv.w, wdj[4 * jj + 3], acc);
        }
        float y = sigf(acc);
        size_t idx = (size_t)row * 64 + lane;
        if (!mix) {
            Y[idx] = y;
        } else {
            float v = y * wm + (init ? 0.f : mix[idx]);
            if (fin) v = sigf(v);
            mix[idx] = v;
        }
    }
}

// One thread per (t,n) cell; sequential over l.
__global__ void lstm_kernel(const float* __restrict__ md, const float* __restrict__ ms,
                            const float* __restrict__ cw, const float* __restrict__ cb,
                            float* __restrict__ hlast) {
    int idx = blockIdx.x * blockDim.x + threadIdx.x;
    if (idx >= kT * kN) return;
    int t = idx / kN, n = idx % kN;
    float h = 0.f, c = 0.f;
    float b0 = cb[0], b1 = cb[1], b2 = cb[2], b3 = cb[3];
    for (int l = 0; l < kL; ++l) {
        size_t ofs = ((size_t)(t * kL + l) * kN + n) * kD;
        const float* xd = md + ofs;
        const float* xs = ms + ofs;
        float g0 = b0 + h * cw[0 * 129 + 128];
        float g1 = b1 + h * cw[1 * 129 + 128];
        float g2 = b2 + h * cw[2 * 129 + 128];
        float g3 = b3 + h * cw[3 * 129 + 128];
#pragma unroll 8
        for (int dd = 0; dd < kD; ++dd) {
            float v = xd[dd];
            g0 = fmaf(v, cw[0 * 129 + dd], g0);
            g1 = fmaf(v, cw[1 * 129 + dd], g1);
            g2 = fmaf(v, cw[2 * 129 + dd], g2);
            g3 = fmaf(v, cw[3 * 129 + dd], g3);
        }
#pragma unroll 8
        for (int dd = 0; dd < kD; ++dd) {
            float v = xs[dd];
            g0 = fmaf(v, cw[0 * 129 + 64 + dd], g0);
            g1 = fmaf(v, cw[1 * 129 + 64 + dd], g1);
            g2 = fmaf(v, cw[2 * 129 + 64 + dd], g2);
            g3 = fmaf(v, cw[3 * 129 + 64 + dd], g3);
        }
        float ii = sigf(g0);
        float ff = sigf(g1);
        float oo = sigf(g2);
        float gt = tanhf(g3);
        c = ff * c + ii * gt;
        h = oo * tanhf(c);
    }
    hlast[idx] = h;
}

// out[t,m] = sigmoid(sum_n h[t,n]*fw[m,n] + fb[m]); one wave per output.
__global__ void final_kernel(const float* __restrict__ h, const float* __restrict__ fw,
                             const float* __restrict__ fb, float* __restrict__ out) {
    int wave = threadIdx.x >> 6, lane = threadIdx.x & 63;
    int o = blockIdx.x * 4 + wave;   // t*N + m
    int t = o / kN, m = o % kN;
    float acc = 0.f;
    for (int n = lane; n < kN; n += 64)
        acc = fmaf(h[t * kN + n], fw[(size_t)m * kN + n], acc);
#pragma unroll
    for (int off = 32; off > 0; off >>= 1) acc += __shfl_xor(acc, off);
    if (lane == 0) out[o] = sigf(acc + fb[m]);
}

extern "C" void kernel_launch(void* const* d_in, const int* in_sizes, int n_in,
                              void* d_out, int out_size, void* d_ws, size_t ws_size,
                              hipStream_t stream) {
    const float* stat   = (const float*)d_in[0];   // (T,L,N,D)
    const float* thre   = (const float*)d_in[1];   // (T,L,N,1)
    const float* dyn0   = (const float*)d_in[2];   // (L,N,D)
    const int*   npoi   = (const int*)d_in[3];
    const int*   nroad  = (const int*)d_in[4];
    const int*   nrec   = (const int*)d_in[5];
    const float* w1     = (const float*)d_in[6];   // (2D, D)
    const float* wq_all = (const float*)d_in[7];   // (2,3,S,D,D)
    const float* wk_all = (const float*)d_in[8];
    const float* wd_all = (const float*)d_in[9];
    const float* wmix   = (const float*)d_in[10];  // (2,3,D)
    const float* conv_w = (const float*)d_in[11];  // (4,129)
    const float* conv_b = (const float*)d_in[12];  // (4,)
    const float* fin_w  = (const float*)d_in[13];  // (N,N)
    const float* fin_b  = (const float*)d_in[14];  // (N,)

    float* out       = (float*)d_out;              // (T,N)
    float* now_final = out + kT * kN;              // (L,N,D)
    float* diffs     = now_final + (size_t)kLN * kD; // (T-1,L,N,D)

    float* ws      = (float*)d_ws;
    float* all_dyn = ws;                           // (T,L,N,D)
    float* b1      = ws + (size_t)kBUF;            // Q / O / xa (in-place chain)
    float* b2      = ws + 2 * (size_t)kBUF;        // XK
    float* mixd    = ws + 3 * (size_t)kBUF;
    float* mixs    = ws + 4 * (size_t)kBUF;
    float* hlast   = ws + 5 * (size_t)kBUF;        // (T,N)

    // ---- evolution scan (sequential over t) ----
    hipMemcpyAsync(all_dyn, dyn0, sizeof(float) * kLN * kD,
                   hipMemcpyDeviceToDevice, stream);
    for (int t = 1; t < kT; ++t) {
        evo_kernel<<<kLN / 32, 256, 0, stream>>>(
            stat + (size_t)t * kLN * kD, thre + (size_t)t * kLN,
            all_dyn + (size_t)(t - 1) * kLN * kD,
            all_dyn + (size_t)t * kLN * kD,
            diffs + (size_t)(t - 1) * kLN * kD, w1);
    }
    hipMemcpyAsync(now_final, all_dyn + (size_t)(kT - 1) * kLN * kD,
                   sizeof(float) * kLN * kD, hipMemcpyDeviceToDevice, stream);

    // ---- two multiattention paths ----
    const int* neighs[3] = {npoi, nroad, nrec};
    for (int m = 0; m < 2; ++m) {
        const float* input = (m == 0) ? all_dyn : stat;
        float* mix = (m == 0) ? mixd : mixs;
        for (int g = 0; g < 3; ++g) {
            size_t o0 = (size_t)((m * 3 + g) * 2 + 0) * kD * kD;
            size_t o1 = (size_t)((m * 3 + g) * 2 + 1) * kD * kD;
            // step s=0: input -> b1
            gemm_qk<<<500, 256, 0, stream>>>(input, wq_all + o0, wk_all + o0, b1, b2);
            score_kernel<<<kTLN / 16, 256, 0, stream>>>(b1, b2, neighs[g], b1);
            gemm_wd<<<1000, 256, 0, stream>>>(b1, wd_all + o0, b1, nullptr, nullptr, 0, 0);
            // step s=1: b1 -> mix accumulation
            gemm_qk<<<500, 256, 0, stream>>>(b1, wq_all + o1, wk_all + o1, b1, b2);
            score_kernel<<<kTLN / 16, 256, 0, stream>>>(b1, b2, neighs[g], b1);
            gemm_wd<<<1000, 256, 0, stream>>>(b1, wd_all + o1, nullptr,
                                              wmix + (size_t)(m * 3 + g) * kD, mix,
                                              (g == 0) ? 1 : 0, (g == 2) ? 1 : 0);
        }
    }

    // ---- LSTM over l, then final projection ----
    lstm_kernel<<<(kT * kN + 255) / 256, 256, 0, stream>>>(mixd, mixs, conv_w, conv_b, hlast);
    final_kernel<<<kT * kN / 4, 256, 0, stream>>>(hlast, fin_w, fin_b, out);
}

// Round 3
// 585.302 us; speedup vs baseline: 5.2190x; 5.2190x over previous
//
#include <hip/hip_runtime.h>
#include <math.h>

namespace {
constexpr int kT = 8, kL = 8, kN = 500, kD = 64, kK = 12;
constexpr int kLN  = kL * kN;        // 4000
constexpr int kTLN = kT * kL * kN;   // 32000
constexpr int kBUF = kTLN * kD;      // 2,048,000 floats
constexpr int XS = 68;               // padded LDS stride for X tiles
}

__device__ __forceinline__ float sigf(float v) { return 1.f / (1.f + __expf(-v)); }

// Stage a 64x64 f32 tile (global row stride 64) into LDS (stride XS); rows clamped to M.
__device__ __forceinline__ void stage_x(const float* __restrict__ src, float* lds,
                                        int row0, int M) {
    int r  = threadIdx.x >> 4;
    int c4 = (threadIdx.x & 15) << 2;
#pragma unroll
    for (int i = 0; i < 4; ++i) {
        int rr  = r + 16 * i;
        int row = row0 + rr;
        row = row < M ? row : M - 1;
        float4 v = *reinterpret_cast<const float4*>(src + (size_t)row * 64 + c4);
        *reinterpret_cast<float4*>(lds + rr * XS + c4) = v;
    }
}

// Stage K x 64 weight (row-major) into LDS, stride 64. K in {64,128}.
template <int K>
__device__ __forceinline__ void stage_w(const float* __restrict__ w, float* lds) {
    const float4* s = reinterpret_cast<const float4*>(w);
    float4* d = reinterpret_cast<float4*>(lds);
#pragma unroll
    for (int i = 0; i < K / 16; ++i)
        d[threadIdx.x + 256 * i] = s[threadIdx.x + 256 * i];
}

// acc[i] += row(4*rblk+i) of Xtile  @  Wtile[:, 4*cblk..+3], K=64.
__device__ __forceinline__ void gemm_core(const float* ldsx, const float* ldsw,
                                          int rblk, int cblk, float4 acc[4]) {
#pragma unroll 4
    for (int k = 0; k < 64; k += 4) {
        float4 xv[4], wv[4];
#pragma unroll
        for (int i = 0; i < 4; ++i)
            xv[i] = *reinterpret_cast<const float4*>(ldsx + (4 * rblk + i) * XS + k);
#pragma unroll
        for (int d = 0; d < 4; ++d)
            wv[d] = *reinterpret_cast<const float4*>(ldsw + (k + d) * 64 + 4 * cblk);
#pragma unroll
        for (int i = 0; i < 4; ++i) {
            acc[i].x = fmaf(xv[i].x, wv[0].x, acc[i].x);
            acc[i].y = fmaf(xv[i].x, wv[0].y, acc[i].y);
            acc[i].z = fmaf(xv[i].x, wv[0].z, acc[i].z);
            acc[i].w = fmaf(xv[i].x, wv[0].w, acc[i].w);
            acc[i].x = fmaf(xv[i].y, wv[1].x, acc[i].x);
            acc[i].y = fmaf(xv[i].y, wv[1].y, acc[i].y);
            acc[i].z = fmaf(xv[i].y, wv[1].z, acc[i].z);
            acc[i].w = fmaf(xv[i].y, wv[1].w, acc[i].w);
            acc[i].x = fmaf(xv[i].z, wv[2].x, acc[i].x);
            acc[i].y = fmaf(xv[i].z, wv[2].y, acc[i].y);
            acc[i].z = fmaf(xv[i].z, wv[2].z, acc[i].z);
            acc[i].w = fmaf(xv[i].z, wv[2].w, acc[i].w);
            acc[i].x = fmaf(xv[i].w, wv[3].x, acc[i].x);
            acc[i].y = fmaf(xv[i].w, wv[3].y, acc[i].y);
            acc[i].z = fmaf(xv[i].w, wv[3].z, acc[i].z);
            acc[i].w = fmaf(xv[i].w, wv[3].w, acc[i].w);
        }
    }
}

// Fused core for two weight matrices sharing the X reads.
__device__ __forceinline__ void gemm_core2(const float* ldsx, const float* ldswa,
                                           const float* ldswb, int rblk, int cblk,
                                           float4 acca[4], float4 accb[4]) {
#pragma unroll 4
    for (int k = 0; k < 64; k += 4) {
        float4 xv[4], wa[4], wb[4];
#pragma unroll
        for (int i = 0; i < 4; ++i)
            xv[i] = *reinterpret_cast<const float4*>(ldsx + (4 * rblk + i) * XS + k);
#pragma unroll
        for (int d = 0; d < 4; ++d) {
            wa[d] = *reinterpret_cast<const float4*>(ldswa + (k + d) * 64 + 4 * cblk);
            wb[d] = *reinterpret_cast<const float4*>(ldswb + (k + d) * 64 + 4 * cblk);
        }
#pragma unroll
        for (int i = 0; i < 4; ++i) {
            float xs[4] = {xv[i].x, xv[i].y, xv[i].z, xv[i].w};
#pragma unroll
            for (int d = 0; d < 4; ++d) {
                acca[i].x = fmaf(xs[d], wa[d].x, acca[i].x);
                acca[i].y = fmaf(xs[d], wa[d].y, acca[i].y);
                acca[i].z = fmaf(xs[d], wa[d].z, acca[i].z);
                acca[i].w = fmaf(xs[d], wa[d].w, acca[i].w);
                accb[i].x = fmaf(xs[d], wb[d].x, accb[i].x);
                accb[i].y = fmaf(xs[d], wb[d].y, accb[i].y);
                accb[i].z = fmaf(xs[d], wb[d].z, accb[i].z);
                accb[i].w = fmaf(xs[d], wb[d].w, accb[i].w);
            }
        }
    }
}

// new = sigmoid(cat(prev,st)@w1 * th + prev*(1-th)); diff = new - prev. M = kLN.
__global__ void __launch_bounds__(256) evo_kernel(const float* __restrict__ st,
                                                  const float* __restrict__ th,
                                                  const float* __restrict__ prev,
                                                  float* __restrict__ cur,
                                                  float* __restrict__ diff,
                                                  const float* __restrict__ w1) {
    __shared__ float ldsn[64 * XS];
    __shared__ float ldss[64 * XS];
    __shared__ float ldsw[128 * 64];
    int row0 = blockIdx.x * 64;
    stage_x(prev, ldsn, row0, kLN);
    stage_x(st, ldss, row0, kLN);
    stage_w<128>(w1, ldsw);
    __syncthreads();
    int rblk = threadIdx.x >> 4, cblk = threadIdx.x & 15;
    float4 acc[4] = {};
    gemm_core(ldsn, ldsw, rblk, cblk, acc);
    gemm_core(ldss, ldsw + 64 * 64, rblk, cblk, acc);
#pragma unroll
    for (int i = 0; i < 4; ++i) {
        int row = row0 + 4 * rblk + i;
        if (row < kLN) {
            float t = th[row];
            float4 xn = *reinterpret_cast<const float4*>(ldsn + (4 * rblk + i) * XS + 4 * cblk);
            float4 nv, df;
            nv.x = sigf(acc[i].x * t + xn.x * (1.f - t));
            nv.y = sigf(acc[i].y * t + xn.y * (1.f - t));
            nv.z = sigf(acc[i].z * t + xn.z * (1.f - t));
            nv.w = sigf(acc[i].w * t + xn.w * (1.f - t));
            df.x = nv.x - xn.x; df.y = nv.y - xn.y;
            df.z = nv.z - xn.z; df.w = nv.w - xn.w;
            *reinterpret_cast<float4*>(cur + (size_t)row * 64 + 4 * cblk) = nv;
            *reinterpret_cast<float4*>(diff + (size_t)row * 64 + 4 * cblk) = df;
        }
    }
}

// Q = X@wq, XK = X@wk (M = kTLN, exact multiple of 64).
__global__ void __launch_bounds__(256) gemm_qk(const float* __restrict__ X,
                                               const float* __restrict__ wq,
                                               const float* __restrict__ wk,
                                               float* __restrict__ Q,
                                               float* __restrict__ XK) {
    __shared__ float ldsx[64 * XS];
    __shared__ float ldswq[64 * 64];
    __shared__ float ldswk[64 * 64];
    int row0 = blockIdx.x * 64;
    stage_x(X, ldsx, row0, kTLN);
    stage_w<64>(wq, ldswq);
    stage_w<64>(wk, ldswk);
    __syncthreads();
    int rblk = threadIdx.x >> 4, cblk = threadIdx.x & 15;
    float4 aq[4] = {}, ak[4] = {};
    gemm_core2(ldsx, ldswq, ldswk, rblk, cblk, aq, ak);
#pragma unroll
    for (int i = 0; i < 4; ++i) {
        size_t row = row0 + 4 * rblk + i;
        *reinterpret_cast<float4*>(Q + row * 64 + 4 * cblk)  = aq[i];
        *reinterpret_cast<float4*>(XK + row * 64 + 4 * cblk) = ak[i];
    }
}

// Scores + softmax + combine (quarter-wave: 16 lanes per row, float4 per lane).
__global__ void score_kernel(const float* __restrict__ Q, const float* __restrict__ XK,
                             const int* __restrict__ neigh, float* __restrict__ O) {
    int lane = threadIdx.x & 63;
    int wave = threadIdx.x >> 6;
    int sub  = lane >> 4;
    int g    = lane & 15;
    int row  = blockIdx.x * 16 + wave * 4 + sub;
    int n    = row % kN;
    int slab = row - n;
    float4 q = *(reinterpret_cast<const float4*>(Q) + (size_t)row * 16 + g);
    const int4* nbp = reinterpret_cast<const int4*>(neigh + n * kK);
    int4 nb0 = nbp[0], nb1 = nbp[1], nb2 = nbp[2];
    int nb[12] = {nb0.x, nb0.y, nb0.z, nb0.w, nb1.x, nb1.y, nb1.z, nb1.w,
                  nb2.x, nb2.y, nb2.z, nb2.w};
    float4 kv[12];
    float sc[12];
#pragma unroll
    for (int j = 0; j < 12; ++j) {
        kv[j] = *(reinterpret_cast<const float4*>(XK) + (size_t)(slab + nb[j]) * 16 + g);
        sc[j] = q.x * kv[j].x + q.y * kv[j].y + q.z * kv[j].z + q.w * kv[j].w;
    }
#pragma unroll
    for (int off = 1; off < 16; off <<= 1) {
#pragma unroll
        for (int j = 0; j < 12; ++j) sc[j] += __shfl_xor(sc[j], off, 16);
    }
    float m = sc[0];
#pragma unroll
    for (int j = 1; j < 12; ++j) m = fmaxf(m, sc[j]);
    float ssum = 0.f;
#pragma unroll
    for (int j = 0; j < 12; ++j) { sc[j] = __expf(sc[j] - m); ssum += sc[j]; }
    float inv = 1.f / ssum;
    float4 o = q;
#pragma unroll
    for (int j = 0; j < 12; ++j) {
        float a = sc[j] * inv;
        o.x = fmaf(a, kv[j].x, o.x);
        o.y = fmaf(a, kv[j].y, o.y);
        o.z = fmaf(a, kv[j].z, o.z);
        o.w = fmaf(a, kv[j].w, o.w);
    }
    *(reinterpret_cast<float4*>(O) + (size_t)row * 16 + g) = o;
}

// Y = sigmoid(O@wd); or mix accumulation (init zeroes, fin applies sigmoid).
__global__ void __launch_bounds__(256) gemm_wd(const float* __restrict__ O,
                                               const float* __restrict__ wd,
                                               float* __restrict__ Y,
                                               const float* __restrict__ wmix,
                                               float* __restrict__ mix,
                                               int init, int fin) {
    __shared__ float ldsx[64 * XS];
    __shared__ float ldsw[64 * 64];
    int row0 = blockIdx.x * 64;
    stage_x(O, ldsx, row0, kTLN);
    stage_w<64>(wd, ldsw);
    __syncthreads();
    int rblk = threadIdx.x >> 4, cblk = threadIdx.x & 15;
    float4 acc[4] = {};
    gemm_core(ldsx, ldsw, rblk, cblk, acc);
    float4 wm = mix ? *reinterpret_cast<const float4*>(wmix + 4 * cblk)
                    : float4{0.f, 0.f, 0.f, 0.f};
#pragma unroll
    for (int i = 0; i < 4; ++i) {
        size_t idx = ((size_t)(row0 + 4 * rblk + i)) * 64 + 4 * cblk;
        float4 y;
        y.x = sigf(acc[i].x); y.y = sigf(acc[i].y);
        y.z = sigf(acc[i].z); y.w = sigf(acc[i].w);
        if (!mix) {
            *reinterpret_cast<float4*>(Y + idx) = y;
        } else {
            float4 v;
            if (init) { v = float4{0.f, 0.f, 0.f, 0.f}; }
            else      { v = *reinterpret_cast<const float4*>(mix + idx); }
            v.x = fmaf(y.x, wm.x, v.x);
            v.y = fmaf(y.y, wm.y, v.y);
            v.z = fmaf(y.z, wm.z, v.z);
            v.w = fmaf(y.w, wm.w, v.w);
            if (fin) { v.x = sigf(v.x); v.y = sigf(v.y); v.z = sigf(v.z); v.w = sigf(v.w); }
            *reinterpret_cast<float4*>(mix + idx) = v;
        }
    }
}

// One thread per (t,n) cell; sequential over l.
__global__ void lstm_kernel(const float* __restrict__ md, const float* __restrict__ ms,
                            const float* __restrict__ cw, const float* __restrict__ cb,
                            float* __restrict__ hlast) {
    int idx = blockIdx.x * blockDim.x + threadIdx.x;
    if (idx >= kT * kN) return;
    int t = idx / kN, n = idx % kN;
    float h = 0.f, c = 0.f;
    float b0 = cb[0], b1 = cb[1], b2 = cb[2], b3 = cb[3];
    for (int l = 0; l < kL; ++l) {
        size_t ofs = ((size_t)(t * kL + l) * kN + n) * kD;
        const float* xd = md + ofs;
        const float* xs = ms + ofs;
        float g0 = b0 + h * cw[0 * 129 + 128];
        float g1 = b1 + h * cw[1 * 129 + 128];
        float g2 = b2 + h * cw[2 * 129 + 128];
        float g3 = b3 + h * cw[3 * 129 + 128];
#pragma unroll 8
        for (int dd = 0; dd < kD; ++dd) {
            float v = xd[dd];
            g0 = fmaf(v, cw[0 * 129 + dd], g0);
            g1 = fmaf(v, cw[1 * 129 + dd], g1);
            g2 = fmaf(v, cw[2 * 129 + dd], g2);
            g3 = fmaf(v, cw[3 * 129 + dd], g3);
        }
#pragma unroll 8
        for (int dd = 0; dd < kD; ++dd) {
            float v = xs[dd];
            g0 = fmaf(v, cw[0 * 129 + 64 + dd], g0);
            g1 = fmaf(v, cw[1 * 129 + 64 + dd], g1);
            g2 = fmaf(v, cw[2 * 129 + 64 + dd], g2);
            g3 = fmaf(v, cw[3 * 129 + 64 + dd], g3);
        }
        float ii = sigf(g0);
        float ff = sigf(g1);
        float oo = sigf(g2);
        float gt = tanhf(g3);
        c = ff * c + ii * gt;
        h = oo * tanhf(c);
    }
    hlast[idx] = h;
}

// out[t,m] = sigmoid(sum_n h[t,n]*fw[m,n] + fb[m]); one wave per output.
__global__ void final_kernel(const float* __restrict__ h, const float* __restrict__ fw,
                             const float* __restrict__ fb, float* __restrict__ out) {
    int wave = threadIdx.x >> 6, lane = threadIdx.x & 63;
    int o = blockIdx.x * 4 + wave;
    int t = o / kN, m = o % kN;
    float acc = 0.f;
    for (int n = lane; n < kN; n += 64)
        acc = fmaf(h[t * kN + n], fw[(size_t)m * kN + n], acc);
#pragma unroll
    for (int off = 32; off > 0; off >>= 1) acc += __shfl_xor(acc, off);
    if (lane == 0) out[o] = sigf(acc + fb[m]);
}

extern "C" void kernel_launch(void* const* d_in, const int* in_sizes, int n_in,
                              void* d_out, int out_size, void* d_ws, size_t ws_size,
                              hipStream_t stream) {
    const float* stat   = (const float*)d_in[0];
    const float* thre   = (const float*)d_in[1];
    const float* dyn0   = (const float*)d_in[2];
    const int*   npoi   = (const int*)d_in[3];
    const int*   nroad  = (const int*)d_in[4];
    const int*   nrec   = (const int*)d_in[5];
    const float* w1     = (const float*)d_in[6];
    const float* wq_all = (const float*)d_in[7];
    const float* wk_all = (const float*)d_in[8];
    const float* wd_all = (const float*)d_in[9];
    const float* wmix   = (const float*)d_in[10];
    const float* conv_w = (const float*)d_in[11];
    const float* conv_b = (const float*)d_in[12];
    const float* fin_w  = (const float*)d_in[13];
    const float* fin_b  = (const float*)d_in[14];

    float* out       = (float*)d_out;                 // (T,N)
    float* now_final = out + kT * kN;                 // (L,N,D)
    float* diffs     = now_final + (size_t)kLN * kD;  // (T-1,L,N,D)

    float* ws      = (float*)d_ws;
    float* all_dyn = ws;                              // (T,L,N,D)
    float* b1      = ws + (size_t)kBUF;               // Q / O chain
    float* b2      = ws + 2 * (size_t)kBUF;           // XK
    float* mixd    = ws + 3 * (size_t)kBUF;
    float* mixs    = ws + 4 * (size_t)kBUF;
    float* hlast   = ws + 5 * (size_t)kBUF;           // (T,N)

    // ---- evolution scan (sequential over t) ----
    hipMemcpyAsync(all_dyn, dyn0, sizeof(float) * kLN * kD,
                   hipMemcpyDeviceToDevice, stream);
    for (int t = 1; t < kT; ++t) {
        evo_kernel<<<(kLN + 63) / 64, 256, 0, stream>>>(
            stat + (size_t)t * kLN * kD, thre + (size_t)t * kLN,
            all_dyn + (size_t)(t - 1) * kLN * kD,
            all_dyn + (size_t)t * kLN * kD,
            diffs + (size_t)(t - 1) * kLN * kD, w1);
    }
    hipMemcpyAsync(now_final, all_dyn + (size_t)(kT - 1) * kLN * kD,
                   sizeof(float) * kLN * kD, hipMemcpyDeviceToDevice, stream);

    // ---- two multiattention paths ----
    const int* neighs[3] = {npoi, nroad, nrec};
    for (int m = 0; m < 2; ++m) {
        const float* input = (m == 0) ? all_dyn : stat;
        float* mix = (m == 0) ? mixd : mixs;
        for (int g = 0; g < 3; ++g) {
            size_t o0 = (size_t)((m * 3 + g) * 2 + 0) * kD * kD;
            size_t o1 = (size_t)((m * 3 + g) * 2 + 1) * kD * kD;
            gemm_qk<<<kTLN / 64, 256, 0, stream>>>(input, wq_all + o0, wk_all + o0, b1, b2);
            score_kernel<<<kTLN / 16, 256, 0, stream>>>(b1, b2, neighs[g], b1);
            gemm_wd<<<kTLN / 64, 256, 0, stream>>>(b1, wd_all + o0, b1,
                                                   nullptr, nullptr, 0, 0);
            gemm_qk<<<kTLN / 64, 256, 0, stream>>>(b1, wq_all + o1, wk_all + o1, b1, b2);
            score_kernel<<<kTLN / 16, 256, 0, stream>>>(b1, b2, neighs[g], b1);
            gemm_wd<<<kTLN / 64, 256, 0, stream>>>(b1, wd_all + o1, nullptr,
                                                   wmix + (size_t)(m * 3 + g) * kD, mix,
                                                   (g == 0) ? 1 : 0, (g == 2) ? 1 : 0);
        }
    }

    // ---- LSTM over l, then final projection ----
    lstm_kernel<<<(kT * kN + 255) / 256, 256, 0, stream>>>(mixd, mixs, conv_w, conv_b, hlast);
    final_kernel<<<kT * kN / 4, 256, 0, stream>>>(hlast, fin_w, fin_b, out);
}

// Round 4
// 410.139 us; speedup vs baseline: 7.4480x; 1.4271x over previous
//
#include <hip/hip_runtime.h>
#include <math.h>

namespace {
constexpr int kT = 8, kL = 8, kN = 500, kD = 64, kK = 12;
constexpr int kLN  = kL * kN;        // 4000
constexpr int kTLN = kT * kL * kN;   // 32000
constexpr int kBUF = kTLN * kD;      // 2,048,000 floats
constexpr int XS = 68;               // padded LDS stride for X tiles
}

__device__ __forceinline__ float sigf(float v) { return 1.f / (1.f + __expf(-v)); }

// Stage a 64x64 f32 tile (global row stride 64) into LDS (stride XS); rows clamped to M.
__device__ __forceinline__ void stage_x(const float* __restrict__ src, float* lds,
                                        int row0, int M) {
    int r  = threadIdx.x >> 4;
    int c4 = (threadIdx.x & 15) << 2;
#pragma unroll
    for (int i = 0; i < 4; ++i) {
        int rr  = r + 16 * i;
        int row = row0 + rr;
        row = row < M ? row : M - 1;
        float4 v = *reinterpret_cast<const float4*>(src + (size_t)row * 64 + c4);
        *reinterpret_cast<float4*>(lds + rr * XS + c4) = v;
    }
}

// Stage K x 64 weight (row-major) into LDS, stride 64. K in {64,128}.
template <int K>
__device__ __forceinline__ void stage_w(const float* __restrict__ w, float* lds) {
    const float4* s = reinterpret_cast<const float4*>(w);
    float4* d = reinterpret_cast<float4*>(lds);
#pragma unroll
    for (int i = 0; i < K / 16; ++i)
        d[threadIdx.x + 256 * i] = s[threadIdx.x + 256 * i];
}

// acc[i] += row(4*rblk+i) of Xtile  @  Wtile[:, 4*cblk..+3], K=64.
__device__ __forceinline__ void gemm_core(const float* ldsx, const float* ldsw,
                                          int rblk, int cblk, float4 acc[4]) {
#pragma unroll 4
    for (int k = 0; k < 64; k += 4) {
        float4 xv[4], wv[4];
#pragma unroll
        for (int i = 0; i < 4; ++i)
            xv[i] = *reinterpret_cast<const float4*>(ldsx + (4 * rblk + i) * XS + k);
#pragma unroll
        for (int d = 0; d < 4; ++d)
            wv[d] = *reinterpret_cast<const float4*>(ldsw + (k + d) * 64 + 4 * cblk);
#pragma unroll
        for (int i = 0; i < 4; ++i) {
            float xs[4] = {xv[i].x, xv[i].y, xv[i].z, xv[i].w};
#pragma unroll
            for (int d = 0; d < 4; ++d) {
                acc[i].x = fmaf(xs[d], wv[d].x, acc[i].x);
                acc[i].y = fmaf(xs[d], wv[d].y, acc[i].y);
                acc[i].z = fmaf(xs[d], wv[d].z, acc[i].z);
                acc[i].w = fmaf(xs[d], wv[d].w, acc[i].w);
            }
        }
    }
}

// Fused core for two weight matrices sharing the X reads.
__device__ __forceinline__ void gemm_core2(const float* ldsx, const float* ldswa,
                                           const float* ldswb, int rblk, int cblk,
                                           float4 acca[4], float4 accb[4]) {
#pragma unroll 4
    for (int k = 0; k < 64; k += 4) {
        float4 xv[4], wa[4], wb[4];
#pragma unroll
        for (int i = 0; i < 4; ++i)
            xv[i] = *reinterpret_cast<const float4*>(ldsx + (4 * rblk + i) * XS + k);
#pragma unroll
        for (int d = 0; d < 4; ++d) {
            wa[d] = *reinterpret_cast<const float4*>(ldswa + (k + d) * 64 + 4 * cblk);
            wb[d] = *reinterpret_cast<const float4*>(ldswb + (k + d) * 64 + 4 * cblk);
        }
#pragma unroll
        for (int i = 0; i < 4; ++i) {
            float xs[4] = {xv[i].x, xv[i].y, xv[i].z, xv[i].w};
#pragma unroll
            for (int d = 0; d < 4; ++d) {
                acca[i].x = fmaf(xs[d], wa[d].x, acca[i].x);
                acca[i].y = fmaf(xs[d], wa[d].y, acca[i].y);
                acca[i].z = fmaf(xs[d], wa[d].z, acca[i].z);
                acca[i].w = fmaf(xs[d], wa[d].w, acca[i].w);
                accb[i].x = fmaf(xs[d], wb[d].x, accb[i].x);
                accb[i].y = fmaf(xs[d], wb[d].y, accb[i].y);
                accb[i].z = fmaf(xs[d], wb[d].z, accb[i].z);
                accb[i].w = fmaf(xs[d], wb[d].w, accb[i].w);
            }
        }
    }
}

// new = sigmoid(cat(prev,st)@w1 * th + prev*(1-th)); diff = new - prev. M = kLN.
__global__ void __launch_bounds__(256) evo_kernel(const float* __restrict__ st,
                                                  const float* __restrict__ th,
                                                  const float* __restrict__ prev,
                                                  float* __restrict__ cur,
                                                  float* __restrict__ diff,
                                                  const float* __restrict__ w1) {
    __shared__ float ldsn[64 * XS];
    __shared__ float ldss[64 * XS];
    __shared__ float ldsw[128 * 64];
    int row0 = blockIdx.x * 64;
    stage_x(prev, ldsn, row0, kLN);
    stage_x(st, ldss, row0, kLN);
    stage_w<128>(w1, ldsw);
    __syncthreads();
    int rblk = threadIdx.x >> 4, cblk = threadIdx.x & 15;
    float4 acc[4] = {};
    gemm_core(ldsn, ldsw, rblk, cblk, acc);
    gemm_core(ldss, ldsw + 64 * 64, rblk, cblk, acc);
#pragma unroll
    for (int i = 0; i < 4; ++i) {
        int row = row0 + 4 * rblk + i;
        if (row < kLN) {
            float t = th[row];
            float4 xn = *reinterpret_cast<const float4*>(ldsn + (4 * rblk + i) * XS + 4 * cblk);
            float4 nv, df;
            nv.x = sigf(acc[i].x * t + xn.x * (1.f - t));
            nv.y = sigf(acc[i].y * t + xn.y * (1.f - t));
            nv.z = sigf(acc[i].z * t + xn.z * (1.f - t));
            nv.w = sigf(acc[i].w * t + xn.w * (1.f - t));
            df.x = nv.x - xn.x; df.y = nv.y - xn.y;
            df.z = nv.z - xn.z; df.w = nv.w - xn.w;
            *reinterpret_cast<float4*>(cur + (size_t)row * 64 + 4 * cblk) = nv;
            *reinterpret_cast<float4*>(diff + (size_t)row * 64 + 4 * cblk) = df;
        }
    }
}

// Batched over 6 chains (blockIdx.y = c = m*3+g). Q (in-place over b1[c]) and
// XK (b2[c]) for attention step `step`. Step0 input: all_dyn (m=0) / stat (m=1);
// step1 input: b1[c] (previous step's y). In-place is safe: each row's X is
// read (staged to LDS) and its Q written only by this tile's workgroup.
__global__ void __launch_bounds__(256) gemm_qk(const float* __restrict__ Xdyn,
                                               const float* __restrict__ Xstat,
                                               const float* __restrict__ wq_all,
                                               const float* __restrict__ wk_all,
                                               float* __restrict__ b1,
                                               float* __restrict__ b2, int step) {
    __shared__ float ldsx[64 * XS];
    __shared__ float ldswq[64 * 64];
    __shared__ float ldswk[64 * 64];
    int c = blockIdx.y;
    int m = c / 3;
    float* b1c = b1 + (size_t)c * kBUF;
    float* b2c = b2 + (size_t)c * kBUF;
    const float* X = step ? b1c : (m == 0 ? Xdyn : Xstat);
    size_t woff = (size_t)(c * 2 + step) * kD * kD;
    int row0 = blockIdx.x * 64;
    stage_x(X, ldsx, row0, kTLN);
    stage_w<64>(wq_all + woff, ldswq);
    stage_w<64>(wk_all + woff, ldswk);
    __syncthreads();
    int rblk = threadIdx.x >> 4, cblk = threadIdx.x & 15;
    float4 aq[4] = {}, ak[4] = {};
    gemm_core2(ldsx, ldswq, ldswk, rblk, cblk, aq, ak);
#pragma unroll
    for (int i = 0; i < 4; ++i) {
        size_t row = row0 + 4 * rblk + i;
        *reinterpret_cast<float4*>(b1c + row * 64 + 4 * cblk) = aq[i];
        *reinterpret_cast<float4*>(b2c + row * 64 + 4 * cblk) = ak[i];
    }
}

// Fused score+softmax+combine+wd, batched over 6 chains. Score phase builds the
// O tile directly in LDS (quarter-wave: 16 lanes/row, float4/lane), then the
// tiled GEMM with wd + sigmoid writes y in-place over b1[c].
__global__ void __launch_bounds__(256) scorewd_kernel(float* __restrict__ b1,
                                                      const float* __restrict__ b2,
                                                      const int* __restrict__ npoi,
                                                      const int* __restrict__ nroad,
                                                      const int* __restrict__ nrec,
                                                      const float* __restrict__ wd_all,
                                                      int step) {
    __shared__ float ldsx[64 * XS];
    __shared__ float ldsw[64 * 64];
    int c = blockIdx.y;
    int g = c % 3;
    float* b1c = b1 + (size_t)c * kBUF;
    const float* b2c = b2 + (size_t)c * kBUF;
    const int* neigh = (g == 0) ? npoi : (g == 1) ? nroad : nrec;
    stage_w<64>(wd_all + (size_t)(c * 2 + step) * kD * kD, ldsw);

    int lane = threadIdx.x & 63;
    int wv   = threadIdx.x >> 6;
    int sub  = lane >> 4;
    int gq   = lane & 15;
    int row0 = blockIdx.x * 64;
#pragma unroll 1
    for (int p = 0; p < 4; ++p) {
        int lr  = p * 16 + wv * 4 + sub;    // local row 0..63
        int row = row0 + lr;
        int n   = row % kN;
        int slab = row - n;
        float4 q = *(reinterpret_cast<const float4*>(b1c) + (size_t)row * 16 + gq);
        const int4* nbp = reinterpret_cast<const int4*>(neigh + n * kK);
        int4 nb0 = nbp[0], nb1 = nbp[1], nb2 = nbp[2];
        int nb[12] = {nb0.x, nb0.y, nb0.z, nb0.w, nb1.x, nb1.y, nb1.z, nb1.w,
                      nb2.x, nb2.y, nb2.z, nb2.w};
        float4 kv[12];
        float sc[12];
#pragma unroll
        for (int j = 0; j < 12; ++j) {
            kv[j] = *(reinterpret_cast<const float4*>(b2c) + (size_t)(slab + nb[j]) * 16 + gq);
            sc[j] = q.x * kv[j].x + q.y * kv[j].y + q.z * kv[j].z + q.w * kv[j].w;
        }
#pragma unroll
        for (int off = 1; off < 16; off <<= 1) {
#pragma unroll
            for (int j = 0; j < 12; ++j) sc[j] += __shfl_xor(sc[j], off, 16);
        }
        float mx = sc[0];
#pragma unroll
        for (int j = 1; j < 12; ++j) mx = fmaxf(mx, sc[j]);
        float ssum = 0.f;
#pragma unroll
        for (int j = 0; j < 12; ++j) { sc[j] = __expf(sc[j] - mx); ssum += sc[j]; }
        float inv = 1.f / ssum;
        float4 o = q;
#pragma unroll
        for (int j = 0; j < 12; ++j) {
            float a = sc[j] * inv;
            o.x = fmaf(a, kv[j].x, o.x);
            o.y = fmaf(a, kv[j].y, o.y);
            o.z = fmaf(a, kv[j].z, o.z);
            o.w = fmaf(a, kv[j].w, o.w);
        }
        *reinterpret_cast<float4*>(ldsx + lr * XS + 4 * gq) = o;
    }
    __syncthreads();
    int rblk = threadIdx.x >> 4, cblk = threadIdx.x & 15;
    float4 acc[4] = {};
    gemm_core(ldsx, ldsw, rblk, cblk, acc);
#pragma unroll
    for (int i = 0; i < 4; ++i) {
        size_t idx = ((size_t)(row0 + 4 * rblk + i)) * 64 + 4 * cblk;
        float4 y;
        y.x = sigf(acc[i].x); y.y = sigf(acc[i].y);
        y.z = sigf(acc[i].z); y.w = sigf(acc[i].w);
        *reinterpret_cast<float4*>(b1c + idx) = y;
    }
}

// mixd/mixs from the 6 per-chain y buffers.
__global__ void mix_kernel(const float* __restrict__ b1, const float* __restrict__ wmix,
                           float* __restrict__ mixd, float* __restrict__ mixs) {
    int i = blockIdx.x * 256 + threadIdx.x;
    int d = i & 63;
    float vd = b1[i] * wmix[0 * 64 + d]
             + b1[i + (size_t)kBUF] * wmix[1 * 64 + d]
             + b1[i + 2 * (size_t)kBUF] * wmix[2 * 64 + d];
    float vs = b1[i + 3 * (size_t)kBUF] * wmix[3 * 64 + d]
             + b1[i + 4 * (size_t)kBUF] * wmix[4 * 64 + d]
             + b1[i + 5 * (size_t)kBUF] * wmix[5 * 64 + d];
    mixd[i] = sigf(vd);
    mixs[i] = sigf(vs);
}

// LSTM: 16 lanes per (t,n) cell (4 cells/wave, 16 cells/block), sequential over l.
__global__ void __launch_bounds__(256) lstm_kernel(const float* __restrict__ md,
                                                   const float* __restrict__ ms,
                                                   const float* __restrict__ cw,
                                                   const float* __restrict__ cb,
                                                   float* __restrict__ hlast) {
    int lane = threadIdx.x & 63;
    int wv   = threadIdx.x >> 6;
    int sub  = lane >> 4;
    int fq   = lane & 15;
    int cell = blockIdx.x * 16 + wv * 4 + sub;   // 0..3999
    int t = cell / kN, n = cell % kN;
    float wd_[4][4], ws_[4][4], wh[4], bb[4];
#pragma unroll
    for (int gg = 0; gg < 4; ++gg) {
#pragma unroll
        for (int k = 0; k < 4; ++k) {
            wd_[gg][k] = cw[gg * 129 + fq * 4 + k];
            ws_[gg][k] = cw[gg * 129 + 64 + fq * 4 + k];
        }
        wh[gg] = cw[gg * 129 + 128];
        bb[gg] = cb[gg];
    }
    float h = 0.f, cc = 0.f;
#pragma unroll 1
    for (int l = 0; l < kL; ++l) {
        size_t row = (size_t)(t * kL + l) * kN + n;
        float4 xd = *(reinterpret_cast<const float4*>(md) + row * 16 + fq);
        float4 xs = *(reinterpret_cast<const float4*>(ms) + row * 16 + fq);
        float gsum[4];
#pragma unroll
        for (int gg = 0; gg < 4; ++gg) {
            float v = xd.x * wd_[gg][0] + xd.y * wd_[gg][1]
                    + xd.z * wd_[gg][2] + xd.w * wd_[gg][3];
            v += xs.x * ws_[gg][0] + xs.y * ws_[gg][1]
               + xs.z * ws_[gg][2] + xs.w * ws_[gg][3];
            gsum[gg] = v;
        }
#pragma unroll
        for (int off = 1; off < 16; off <<= 1) {
#pragma unroll
            for (int gg = 0; gg < 4; ++gg) gsum[gg] += __shfl_xor(gsum[gg], off, 16);
        }
        float gi = sigf(gsum[0] + bb[0] + h * wh[0]);
        float gf = sigf(gsum[1] + bb[1] + h * wh[1]);
        float go = sigf(gsum[2] + bb[2] + h * wh[2]);
        float gg_ = tanhf(gsum[3] + bb[3] + h * wh[3]);
        cc = gf * cc + gi * gg_;
        h = go * tanhf(cc);
    }
    if (fq == 0) hlast[cell] = h;
}

// out[t,m] = sigmoid(sum_n h[t,n]*fw[m,n] + fb[m]); one wave per output.
__global__ void final_kernel(const float* __restrict__ h, const float* __restrict__ fw,
                             const float* __restrict__ fb, float* __restrict__ out) {
    int wave = threadIdx.x >> 6, lane = threadIdx.x & 63;
    int o = blockIdx.x * 4 + wave;
    int t = o / kN, m = o % kN;
    float acc = 0.f;
    for (int n = lane; n < kN; n += 64)
        acc = fmaf(h[t * kN + n], fw[(size_t)m * kN + n], acc);
#pragma unroll
    for (int off = 32; off > 0; off >>= 1) acc += __shfl_xor(acc, off);
    if (lane == 0) out[o] = sigf(acc + fb[m]);
}

extern "C" void kernel_launch(void* const* d_in, const int* in_sizes, int n_in,
                              void* d_out, int out_size, void* d_ws, size_t ws_size,
                              hipStream_t stream) {
    const float* stat   = (const float*)d_in[0];
    const float* thre   = (const float*)d_in[1];
    const float* dyn0   = (const float*)d_in[2];
    const int*   npoi   = (const int*)d_in[3];
    const int*   nroad  = (const int*)d_in[4];
    const int*   nrec   = (const int*)d_in[5];
    const float* w1     = (const float*)d_in[6];
    const float* wq_all = (const float*)d_in[7];
    const float* wk_all = (const float*)d_in[8];
    const float* wd_all = (const float*)d_in[9];
    const float* wmix   = (const float*)d_in[10];
    const float* conv_w = (const float*)d_in[11];
    const float* conv_b = (const float*)d_in[12];
    const float* fin_w  = (const float*)d_in[13];
    const float* fin_b  = (const float*)d_in[14];

    float* out       = (float*)d_out;                 // (T,N)
    float* now_final = out + kT * kN;                 // (L,N,D)
    float* diffs     = now_final + (size_t)kLN * kD;  // (T-1,L,N,D)

    float* ws      = (float*)d_ws;
    float* all_dyn = ws;                              // (T,L,N,D)
    float* b1      = ws + (size_t)kBUF;               // 6 x Q/y chain buffers
    float* b2      = ws + 7 * (size_t)kBUF;           // 6 x XK buffers
    float* mixd    = ws + 13 * (size_t)kBUF;
    float* mixs    = ws + 14 * (size_t)kBUF;
    float* hlast   = ws + 15 * (size_t)kBUF;          // (T,N)

    // ---- evolution scan (sequential over t) ----
    hipMemcpyAsync(all_dyn, dyn0, sizeof(float) * kLN * kD,
                   hipMemcpyDeviceToDevice, stream);
    for (int t = 1; t < kT; ++t) {
        evo_kernel<<<(kLN + 63) / 64, 256, 0, stream>>>(
            stat + (size_t)t * kLN * kD, thre + (size_t)t * kLN,
            all_dyn + (size_t)(t - 1) * kLN * kD,
            all_dyn + (size_t)t * kLN * kD,
            diffs + (size_t)(t - 1) * kLN * kD, w1);
    }
    hipMemcpyAsync(now_final, all_dyn + (size_t)(kT - 1) * kLN * kD,
                   sizeof(float) * kLN * kD, hipMemcpyDeviceToDevice, stream);

    // ---- attention: 6 chains batched, 2 steps ----
    dim3 agrid(kTLN / 64, 6);
    gemm_qk<<<agrid, 256, 0, stream>>>(all_dyn, stat, wq_all, wk_all, b1, b2, 0);
    scorewd_kernel<<<agrid, 256, 0, stream>>>(b1, b2, npoi, nroad, nrec, wd_all, 0);
    gemm_qk<<<agrid, 256, 0, stream>>>(all_dyn, stat, wq_all, wk_all, b1, b2, 1);
    scorewd_kernel<<<agrid, 256, 0, stream>>>(b1, b2, npoi, nroad, nrec, wd_all, 1);
    mix_kernel<<<kBUF / 256, 256, 0, stream>>>(b1, wmix, mixd, mixs);

    // ---- LSTM over l, then final projection ----
    lstm_kernel<<<kT * kN / 16, 256, 0, stream>>>(mixd, mixs, conv_w, conv_b, hlast);
    final_kernel<<<kT * kN / 4, 256, 0, stream>>>(hlast, fin_w, fin_b, out);
}

// Round 5
// 361.634 us; speedup vs baseline: 8.4470x; 1.1341x over previous
//
#include <hip/hip_runtime.h>
#include <math.h>

namespace {
constexpr int kT = 8, kL = 8, kN = 500, kD = 64, kK = 12;
constexpr int kLN  = kL * kN;        // 4000
constexpr int kTLN = kT * kL * kN;   // 32000
constexpr int kBUF = kTLN * kD;      // 2,048,000 floats
constexpr int XS = 68;               // padded LDS stride for X tiles
}

__device__ __forceinline__ float sigf(float v) { return 1.f / (1.f + __expf(-v)); }

// Stage a 64x64 f32 tile (global row stride 64) into LDS (stride XS); rows clamped to M.
__device__ __forceinline__ void stage_x(const float* __restrict__ src, float* lds,
                                        int row0, int M) {
    int r  = threadIdx.x >> 4;
    int c4 = (threadIdx.x & 15) << 2;
#pragma unroll
    for (int i = 0; i < 4; ++i) {
        int rr  = r + 16 * i;
        int row = row0 + rr;
        row = row < M ? row : M - 1;
        float4 v = *reinterpret_cast<const float4*>(src + (size_t)row * 64 + c4);
        *reinterpret_cast<float4*>(lds + rr * XS + c4) = v;
    }
}

// Stage K x 64 weight (row-major) into LDS, stride 64. K in {64,128}.
template <int K>
__device__ __forceinline__ void stage_w(const float* __restrict__ w, float* lds) {
    const float4* s = reinterpret_cast<const float4*>(w);
    float4* d = reinterpret_cast<float4*>(lds);
#pragma unroll
    for (int i = 0; i < K / 16; ++i)
        d[threadIdx.x + 256 * i] = s[threadIdx.x + 256 * i];
}

// acc[i] += row(4*rblk+i) of Xtile  @  Wtile[:, 4*cblk..+3], K=64.
__device__ __forceinline__ void gemm_core(const float* ldsx, const float* ldsw,
                                          int rblk, int cblk, float4 acc[4]) {
#pragma unroll 4
    for (int k = 0; k < 64; k += 4) {
        float4 xv[4], wv[4];
#pragma unroll
        for (int i = 0; i < 4; ++i)
            xv[i] = *reinterpret_cast<const float4*>(ldsx + (4 * rblk + i) * XS + k);
#pragma unroll
        for (int d = 0; d < 4; ++d)
            wv[d] = *reinterpret_cast<const float4*>(ldsw + (k + d) * 64 + 4 * cblk);
#pragma unroll
        for (int i = 0; i < 4; ++i) {
            float xs[4] = {xv[i].x, xv[i].y, xv[i].z, xv[i].w};
#pragma unroll
            for (int d = 0; d < 4; ++d) {
                acc[i].x = fmaf(xs[d], wv[d].x, acc[i].x);
                acc[i].y = fmaf(xs[d], wv[d].y, acc[i].y);
                acc[i].z = fmaf(xs[d], wv[d].z, acc[i].z);
                acc[i].w = fmaf(xs[d], wv[d].w, acc[i].w);
            }
        }
    }
}

// Fused core for two weight matrices sharing the X reads.
__device__ __forceinline__ void gemm_core2(const float* ldsx, const float* ldswa,
                                           const float* ldswb, int rblk, int cblk,
                                           float4 acca[4], float4 accb[4]) {
#pragma unroll 4
    for (int k = 0; k < 64; k += 4) {
        float4 xv[4], wa[4], wb[4];
#pragma unroll
        for (int i = 0; i < 4; ++i)
            xv[i] = *reinterpret_cast<const float4*>(ldsx + (4 * rblk + i) * XS + k);
#pragma unroll
        for (int d = 0; d < 4; ++d) {
            wa[d] = *reinterpret_cast<const float4*>(ldswa + (k + d) * 64 + 4 * cblk);
            wb[d] = *reinterpret_cast<const float4*>(ldswb + (k + d) * 64 + 4 * cblk);
        }
#pragma unroll
        for (int i = 0; i < 4; ++i) {
            float xs[4] = {xv[i].x, xv[i].y, xv[i].z, xv[i].w};
#pragma unroll
            for (int d = 0; d < 4; ++d) {
                acca[i].x = fmaf(xs[d], wa[d].x, acca[i].x);
                acca[i].y = fmaf(xs[d], wa[d].y, acca[i].y);
                acca[i].z = fmaf(xs[d], wa[d].z, acca[i].z);
                acca[i].w = fmaf(xs[d], wa[d].w, acca[i].w);
                accb[i].x = fmaf(xs[d], wb[d].x, accb[i].x);
                accb[i].y = fmaf(xs[d], wb[d].y, accb[i].y);
                accb[i].z = fmaf(xs[d], wb[d].z, accb[i].z);
                accb[i].w = fmaf(xs[d], wb[d].w, accb[i].w);
            }
        }
    }
}

// Full evolution scan in ONE kernel: the recurrence is row-local, so each block
// owns 64 rows and loops t=1..7 internally. prev-tile and w1 persist in LDS.
__global__ void __launch_bounds__(256) evo_all_kernel(const float* __restrict__ stat,
                                                      const float* __restrict__ thre,
                                                      const float* __restrict__ dyn0,
                                                      float* __restrict__ all_dyn,
                                                      float* __restrict__ diff,
                                                      const float* __restrict__ w1) {
    __shared__ float ldsn[64 * XS];
    __shared__ float ldss[64 * XS];
    __shared__ float ldsw[128 * 64];
    int row0 = blockIdx.x * 64;
    stage_x(dyn0, ldsn, row0, kLN);
    stage_w<128>(w1, ldsw);
    int rblk = threadIdx.x >> 4, cblk = threadIdx.x & 15;
#pragma unroll 1
    for (int t = 1; t < kT; ++t) {
        stage_x(stat + (size_t)t * kLN * kD, ldss, row0, kLN);
        __syncthreads();
        float4 acc[4] = {};
        gemm_core(ldsn, ldsw, rblk, cblk, acc);
        gemm_core(ldss, ldsw + 64 * 64, rblk, cblk, acc);
        float4 nv[4];
#pragma unroll
        for (int i = 0; i < 4; ++i) {
            int row = row0 + 4 * rblk + i;
            int rc  = row < kLN ? row : kLN - 1;
            float tt = thre[t * kLN + rc];
            float4 xn = *reinterpret_cast<const float4*>(ldsn + (4 * rblk + i) * XS + 4 * cblk);
            nv[i].x = sigf(acc[i].x * tt + xn.x * (1.f - tt));
            nv[i].y = sigf(acc[i].y * tt + xn.y * (1.f - tt));
            nv[i].z = sigf(acc[i].z * tt + xn.z * (1.f - tt));
            nv[i].w = sigf(acc[i].w * tt + xn.w * (1.f - tt));
            if (row < kLN) {
                float4 df;
                df.x = nv[i].x - xn.x; df.y = nv[i].y - xn.y;
                df.z = nv[i].z - xn.z; df.w = nv[i].w - xn.w;
                *reinterpret_cast<float4*>(all_dyn + ((size_t)t * kLN + row) * 64 + 4 * cblk) = nv[i];
                *reinterpret_cast<float4*>(diff + ((size_t)(t - 1) * kLN + row) * 64 + 4 * cblk) = df;
            }
        }
        __syncthreads();   // all reads of ldsn/ldss done before overwrite
#pragma unroll
        for (int i = 0; i < 4; ++i)
            *reinterpret_cast<float4*>(ldsn + (4 * rblk + i) * XS + 4 * cblk) = nv[i];
    }
}

// Batched over 6 chains (blockIdx.y = c = m*3+g). Q (in-place over b1[c]) and
// XK (b2[c]) for attention step `step`.
__global__ void __launch_bounds__(256) gemm_qk(const float* __restrict__ Xdyn,
                                               const float* __restrict__ Xstat,
                                               const float* __restrict__ wq_all,
                                               const float* __restrict__ wk_all,
                                               float* __restrict__ b1,
                                               float* __restrict__ b2, int step) {
    __shared__ float ldsx[64 * XS];
    __shared__ float ldswq[64 * 64];
    __shared__ float ldswk[64 * 64];
    int c = blockIdx.y;
    int m = c / 3;
    float* b1c = b1 + (size_t)c * kBUF;
    float* b2c = b2 + (size_t)c * kBUF;
    const float* X = step ? b1c : (m == 0 ? Xdyn : Xstat);
    size_t woff = (size_t)(c * 2 + step) * kD * kD;
    int row0 = blockIdx.x * 64;
    stage_x(X, ldsx, row0, kTLN);
    stage_w<64>(wq_all + woff, ldswq);
    stage_w<64>(wk_all + woff, ldswk);
    __syncthreads();
    int rblk = threadIdx.x >> 4, cblk = threadIdx.x & 15;
    float4 aq[4] = {}, ak[4] = {};
    gemm_core2(ldsx, ldswq, ldswk, rblk, cblk, aq, ak);
#pragma unroll
    for (int i = 0; i < 4; ++i) {
        size_t row = row0 + 4 * rblk + i;
        *reinterpret_cast<float4*>(b1c + row * 64 + 4 * cblk) = aq[i];
        *reinterpret_cast<float4*>(b2c + row * 64 + 4 * cblk) = ak[i];
    }
}

// Fused score+softmax+combine+wd, batched over 6 chains, with XCD-aware block
// remap: linear dispatch id p -> xcd = p%8 owns a contiguous run of tiles of
// ONE chain, so the 128KB-per-slab XK gather footprint stays hot in that
// XCD's private L2 (grid 500x6 = 3000 blocks = 8 x 375 exactly).
__global__ void __launch_bounds__(256) scorewd_kernel(float* __restrict__ b1,
                                                      const float* __restrict__ b2,
                                                      const int* __restrict__ npoi,
                                                      const int* __restrict__ nroad,
                                                      const int* __restrict__ nrec,
                                                      const float* __restrict__ wd_all,
                                                      int step) {
    __shared__ float ldsx[64 * XS];
    __shared__ float ldsw[64 * 64];
    int p   = blockIdx.y * gridDim.x + blockIdx.x;
    int xcd = p & 7;
    int gid = xcd * 375 + (p >> 3);      // 0..2999
    int c    = gid / 500;
    int tile = gid - c * 500;
    int g = c % 3;
    float* b1c = b1 + (size_t)c * kBUF;
    const float* b2c = b2 + (size_t)c * kBUF;
    const int* neigh = (g == 0) ? npoi : (g == 1) ? nroad : nrec;
    stage_w<64>(wd_all + (size_t)(c * 2 + step) * kD * kD, ldsw);

    int lane = threadIdx.x & 63;
    int wv   = threadIdx.x >> 6;
    int sub  = lane >> 4;
    int gq   = lane & 15;
    int row0 = tile * 64;
#pragma unroll 1
    for (int pp = 0; pp < 4; ++pp) {
        int lr  = pp * 16 + wv * 4 + sub;    // local row 0..63
        int row = row0 + lr;
        int n   = row % kN;
        int slab = row - n;
        float4 q = *(reinterpret_cast<const float4*>(b1c) + (size_t)row * 16 + gq);
        const int4* nbp = reinterpret_cast<const int4*>(neigh + n * kK);
        int4 nb0 = nbp[0], nb1 = nbp[1], nb2 = nbp[2];
        int nb[12] = {nb0.x, nb0.y, nb0.z, nb0.w, nb1.x, nb1.y, nb1.z, nb1.w,
                      nb2.x, nb2.y, nb2.z, nb2.w};
        float4 kv[12];
        float sc[12];
#pragma unroll
        for (int j = 0; j < 12; ++j) {
            kv[j] = *(reinterpret_cast<const float4*>(b2c) + (size_t)(slab + nb[j]) * 16 + gq);
            sc[j] = q.x * kv[j].x + q.y * kv[j].y + q.z * kv[j].z + q.w * kv[j].w;
        }
#pragma unroll
        for (int off = 1; off < 16; off <<= 1) {
#pragma unroll
            for (int j = 0; j < 12; ++j) sc[j] += __shfl_xor(sc[j], off, 16);
        }
        float mx = sc[0];
#pragma unroll
        for (int j = 1; j < 12; ++j) mx = fmaxf(mx, sc[j]);
        float ssum = 0.f;
#pragma unroll
        for (int j = 0; j < 12; ++j) { sc[j] = __expf(sc[j] - mx); ssum += sc[j]; }
        float inv = 1.f / ssum;
        float4 o = q;
#pragma unroll
        for (int j = 0; j < 12; ++j) {
            float a = sc[j] * inv;
            o.x = fmaf(a, kv[j].x, o.x);
            o.y = fmaf(a, kv[j].y, o.y);
            o.z = fmaf(a, kv[j].z, o.z);
            o.w = fmaf(a, kv[j].w, o.w);
        }
        *reinterpret_cast<float4*>(ldsx + lr * XS + 4 * gq) = o;
    }
    __syncthreads();
    int rblk = threadIdx.x >> 4, cblk = threadIdx.x & 15;
    float4 acc[4] = {};
    gemm_core(ldsx, ldsw, rblk, cblk, acc);
#pragma unroll
    for (int i = 0; i < 4; ++i) {
        size_t idx = ((size_t)(row0 + 4 * rblk + i)) * 64 + 4 * cblk;
        float4 y;
        y.x = sigf(acc[i].x); y.y = sigf(acc[i].y);
        y.z = sigf(acc[i].z); y.w = sigf(acc[i].w);
        *reinterpret_cast<float4*>(b1c + idx) = y;
    }
}

// mixd/mixs from the 6 per-chain y buffers.
__global__ void mix_kernel(const float* __restrict__ b1, const float* __restrict__ wmix,
                           float* __restrict__ mixd, float* __restrict__ mixs) {
    int i = blockIdx.x * 256 + threadIdx.x;
    int d = i & 63;
    float vd = b1[i] * wmix[0 * 64 + d]
             + b1[i + (size_t)kBUF] * wmix[1 * 64 + d]
             + b1[i + 2 * (size_t)kBUF] * wmix[2 * 64 + d];
    float vs = b1[i + 3 * (size_t)kBUF] * wmix[3 * 64 + d]
             + b1[i + 4 * (size_t)kBUF] * wmix[4 * 64 + d]
             + b1[i + 5 * (size_t)kBUF] * wmix[5 * 64 + d];
    mixd[i] = sigf(vd);
    mixs[i] = sigf(vs);
}

// LSTM: 16 lanes per (t,n) cell (4 cells/wave, 16 cells/block), sequential over l.
__global__ void __launch_bounds__(256) lstm_kernel(const float* __restrict__ md,
                                                   const float* __restrict__ ms,
                                                   const float* __restrict__ cw,
                                                   const float* __restrict__ cb,
                                                   float* __restrict__ hlast) {
    int lane = threadIdx.x & 63;
    int wv   = threadIdx.x >> 6;
    int sub  = lane >> 4;
    int fq   = lane & 15;
    int cell = blockIdx.x * 16 + wv * 4 + sub;   // 0..3999
    int t = cell / kN, n = cell % kN;
    float wd_[4][4], ws_[4][4], wh[4], bb[4];
#pragma unroll
    for (int gg = 0; gg < 4; ++gg) {
#pragma unroll
        for (int k = 0; k < 4; ++k) {
            wd_[gg][k] = cw[gg * 129 + fq * 4 + k];
            ws_[gg][k] = cw[gg * 129 + 64 + fq * 4 + k];
        }
        wh[gg] = cw[gg * 129 + 128];
        bb[gg] = cb[gg];
    }
    float h = 0.f, cc = 0.f;
#pragma unroll 1
    for (int l = 0; l < kL; ++l) {
        size_t row = (size_t)(t * kL + l) * kN + n;
        float4 xd = *(reinterpret_cast<const float4*>(md) + row * 16 + fq);
        float4 xs = *(reinterpret_cast<const float4*>(ms) + row * 16 + fq);
        float gsum[4];
#pragma unroll
        for (int gg = 0; gg < 4; ++gg) {
            float v = xd.x * wd_[gg][0] + xd.y * wd_[gg][1]
                    + xd.z * wd_[gg][2] + xd.w * wd_[gg][3];
            v += xs.x * ws_[gg][0] + xs.y * ws_[gg][1]
               + xs.z * ws_[gg][2] + xs.w * ws_[gg][3];
            gsum[gg] = v;
        }
#pragma unroll
        for (int off = 1; off < 16; off <<= 1) {
#pragma unroll
            for (int gg = 0; gg < 4; ++gg) gsum[gg] += __shfl_xor(gsum[gg], off, 16);
        }
        float gi = sigf(gsum[0] + bb[0] + h * wh[0]);
        float gf = sigf(gsum[1] + bb[1] + h * wh[1]);
        float go = sigf(gsum[2] + bb[2] + h * wh[2]);
        float gg_ = tanhf(gsum[3] + bb[3] + h * wh[3]);
        cc = gf * cc + gi * gg_;
        h = go * tanhf(cc);
    }
    if (fq == 0) hlast[cell] = h;
}

// out[t,m] = sigmoid(sum_n h[t,n]*fw[m,n] + fb[m]); one wave per output.
__global__ void final_kernel(const float* __restrict__ h, const float* __restrict__ fw,
                             const float* __restrict__ fb, float* __restrict__ out) {
    int wave = threadIdx.x >> 6, lane = threadIdx.x & 63;
    int o = blockIdx.x * 4 + wave;
    int t = o / kN, m = o % kN;
    float acc = 0.f;
    for (int n = lane; n < kN; n += 64)
        acc = fmaf(h[t * kN + n], fw[(size_t)m * kN + n], acc);
#pragma unroll
    for (int off = 32; off > 0; off >>= 1) acc += __shfl_xor(acc, off);
    if (lane == 0) out[o] = sigf(acc + fb[m]);
}

extern "C" void kernel_launch(void* const* d_in, const int* in_sizes, int n_in,
                              void* d_out, int out_size, void* d_ws, size_t ws_size,
                              hipStream_t stream) {
    const float* stat   = (const float*)d_in[0];
    const float* thre   = (const float*)d_in[1];
    const float* dyn0   = (const float*)d_in[2];
    const int*   npoi   = (const int*)d_in[3];
    const int*   nroad  = (const int*)d_in[4];
    const int*   nrec   = (const int*)d_in[5];
    const float* w1     = (const float*)d_in[6];
    const float* wq_all = (const float*)d_in[7];
    const float* wk_all = (const float*)d_in[8];
    const float* wd_all = (const float*)d_in[9];
    const float* wmix   = (const float*)d_in[10];
    const float* conv_w = (const float*)d_in[11];
    const float* conv_b = (const float*)d_in[12];
    const float* fin_w  = (const float*)d_in[13];
    const float* fin_b  = (const float*)d_in[14];

    float* out       = (float*)d_out;                 // (T,N)
    float* now_final = out + kT * kN;                 // (L,N,D)
    float* diffs     = now_final + (size_t)kLN * kD;  // (T-1,L,N,D)

    float* ws      = (float*)d_ws;
    float* all_dyn = ws;                              // (T,L,N,D)
    float* b1      = ws + (size_t)kBUF;               // 6 x Q/y chain buffers
    float* b2      = ws + 7 * (size_t)kBUF;           // 6 x XK buffers
    float* mixd    = ws + 13 * (size_t)kBUF;
    float* mixs    = ws + 14 * (size_t)kBUF;
    float* hlast   = ws + 15 * (size_t)kBUF;          // (T,N)

    // ---- evolution scan: one kernel (row-local recurrence) ----
    hipMemcpyAsync(all_dyn, dyn0, sizeof(float) * kLN * kD,
                   hipMemcpyDeviceToDevice, stream);
    evo_all_kernel<<<(kLN + 63) / 64, 256, 0, stream>>>(stat, thre, dyn0,
                                                        all_dyn, diffs, w1);
    hipMemcpyAsync(now_final, all_dyn + (size_t)(kT - 1) * kLN * kD,
                   sizeof(float) * kLN * kD, hipMemcpyDeviceToDevice, stream);

    // ---- attention: 6 chains batched, 2 steps ----
    dim3 agrid(kTLN / 64, 6);
    gemm_qk<<<agrid, 256, 0, stream>>>(all_dyn, stat, wq_all, wk_all, b1, b2, 0);
    scorewd_kernel<<<agrid, 256, 0, stream>>>(b1, b2, npoi, nroad, nrec, wd_all, 0);
    gemm_qk<<<agrid, 256, 0, stream>>>(all_dyn, stat, wq_all, wk_all, b1, b2, 1);
    scorewd_kernel<<<agrid, 256, 0, stream>>>(b1, b2, npoi, nroad, nrec, wd_all, 1);
    mix_kernel<<<kBUF / 256, 256, 0, stream>>>(b1, wmix, mixd, mixs);

    // ---- LSTM over l, then final projection ----
    lstm_kernel<<<kT * kN / 16, 256, 0, stream>>>(mixd, mixs, conv_w, conv_b, hlast);
    final_kernel<<<kT * kN / 4, 256, 0, stream>>>(hlast, fin_w, fin_b, out);
}

// Round 6
// 350.725 us; speedup vs baseline: 8.7097x; 1.0311x over previous
//
#include <hip/hip_runtime.h>
#include <math.h>

namespace {
constexpr int kT = 8, kL = 8, kN = 500, kD = 64, kK = 12;
constexpr int kLN  = kL * kN;        // 4000
constexpr int kTLN = kT * kL * kN;   // 32000
constexpr int kBUF = kTLN * kD;      // 2,048,000 floats
constexpr int XS = 68;               // padded LDS stride for X tiles
}

__device__ __forceinline__ float sigf(float v) { return 1.f / (1.f + __expf(-v)); }

// Stage a 64x64 f32 tile (global row stride 64) into LDS (stride XS); rows clamped to M.
__device__ __forceinline__ void stage_x(const float* __restrict__ src, float* lds,
                                        int row0, int M) {
    int r  = threadIdx.x >> 4;
    int c4 = (threadIdx.x & 15) << 2;
#pragma unroll
    for (int i = 0; i < 4; ++i) {
        int rr  = r + 16 * i;
        int row = row0 + rr;
        row = row < M ? row : M - 1;
        float4 v = *reinterpret_cast<const float4*>(src + (size_t)row * 64 + c4);
        *reinterpret_cast<float4*>(lds + rr * XS + c4) = v;
    }
}

// Stage K x 64 weight (row-major) into LDS, stride 64. K in {64,128}.
template <int K>
__device__ __forceinline__ void stage_w(const float* __restrict__ w, float* lds) {
    const float4* s = reinterpret_cast<const float4*>(w);
    float4* d = reinterpret_cast<float4*>(lds);
#pragma unroll
    for (int i = 0; i < K / 16; ++i)
        d[threadIdx.x + 256 * i] = s[threadIdx.x + 256 * i];
}

// acc[i] += row(4*rblk+i) of Xtile @ Wtile[:, 4*cblk..+3], K=64. W in LDS.
__device__ __forceinline__ void gemm_core(const float* ldsx, const float* ldsw,
                                          int rblk, int cblk, float4 acc[4]) {
#pragma unroll 4
    for (int k = 0; k < 64; k += 4) {
        float4 xv[4], wv[4];
#pragma unroll
        for (int i = 0; i < 4; ++i)
            xv[i] = *reinterpret_cast<const float4*>(ldsx + (4 * rblk + i) * XS + k);
#pragma unroll
        for (int d = 0; d < 4; ++d)
            wv[d] = *reinterpret_cast<const float4*>(ldsw + (k + d) * 64 + 4 * cblk);
#pragma unroll
        for (int i = 0; i < 4; ++i) {
            float xs[4] = {xv[i].x, xv[i].y, xv[i].z, xv[i].w};
#pragma unroll
            for (int d = 0; d < 4; ++d) {
                acc[i].x = fmaf(xs[d], wv[d].x, acc[i].x);
                acc[i].y = fmaf(xs[d], wv[d].y, acc[i].y);
                acc[i].z = fmaf(xs[d], wv[d].z, acc[i].z);
                acc[i].w = fmaf(xs[d], wv[d].w, acc[i].w);
            }
        }
    }
}

// Same, but W read directly from global (16KB, L1-resident: every block reuses it).
__device__ __forceinline__ void gemm_core_gw(const float* ldsx,
                                             const float* __restrict__ gw,
                                             int rblk, int cblk, float4 acc[4]) {
#pragma unroll 4
    for (int k = 0; k < 64; k += 4) {
        float4 xv[4], wv[4];
#pragma unroll
        for (int i = 0; i < 4; ++i)
            xv[i] = *reinterpret_cast<const float4*>(ldsx + (4 * rblk + i) * XS + k);
#pragma unroll
        for (int d = 0; d < 4; ++d)
            wv[d] = *reinterpret_cast<const float4*>(gw + (k + d) * 64 + 4 * cblk);
#pragma unroll
        for (int i = 0; i < 4; ++i) {
            float xs[4] = {xv[i].x, xv[i].y, xv[i].z, xv[i].w};
#pragma unroll
            for (int d = 0; d < 4; ++d) {
                acc[i].x = fmaf(xs[d], wv[d].x, acc[i].x);
                acc[i].y = fmaf(xs[d], wv[d].y, acc[i].y);
                acc[i].z = fmaf(xs[d], wv[d].z, acc[i].z);
                acc[i].w = fmaf(xs[d], wv[d].w, acc[i].w);
            }
        }
    }
}

// Fused core for two weight matrices (LDS) sharing the X reads.
__device__ __forceinline__ void gemm_core2(const float* ldsx, const float* ldswa,
                                           const float* ldswb, int rblk, int cblk,
                                           float4 acca[4], float4 accb[4]) {
#pragma unroll 4
    for (int k = 0; k < 64; k += 4) {
        float4 xv[4], wa[4], wb[4];
#pragma unroll
        for (int i = 0; i < 4; ++i)
            xv[i] = *reinterpret_cast<const float4*>(ldsx + (4 * rblk + i) * XS + k);
#pragma unroll
        for (int d = 0; d < 4; ++d) {
            wa[d] = *reinterpret_cast<const float4*>(ldswa + (k + d) * 64 + 4 * cblk);
            wb[d] = *reinterpret_cast<const float4*>(ldswb + (k + d) * 64 + 4 * cblk);
        }
#pragma unroll
        for (int i = 0; i < 4; ++i) {
            float xs[4] = {xv[i].x, xv[i].y, xv[i].z, xv[i].w};
#pragma unroll
            for (int d = 0; d < 4; ++d) {
                acca[i].x = fmaf(xs[d], wa[d].x, acca[i].x);
                acca[i].y = fmaf(xs[d], wa[d].y, acca[i].y);
                acca[i].z = fmaf(xs[d], wa[d].z, acca[i].z);
                acca[i].w = fmaf(xs[d], wa[d].w, acca[i].w);
                accb[i].x = fmaf(xs[d], wb[d].x, accb[i].x);
                accb[i].y = fmaf(xs[d], wb[d].y, accb[i].y);
                accb[i].z = fmaf(xs[d], wb[d].z, accb[i].z);
                accb[i].w = fmaf(xs[d], wb[d].w, accb[i].w);
            }
        }
    }
}

// Full evolution scan in ONE kernel (row-local recurrence). Also emits the t=0
// slab of all_dyn (copy of dyn0) and now_final (t=T-1 state) — no memcpys.
__global__ void __launch_bounds__(256) evo_all_kernel(const float* __restrict__ stat,
                                                      const float* __restrict__ thre,
                                                      const float* __restrict__ dyn0,
                                                      float* __restrict__ all_dyn,
                                                      float* __restrict__ diff,
                                                      float* __restrict__ now_final,
                                                      const float* __restrict__ w1) {
    __shared__ float ldsn[64 * XS];
    __shared__ float ldss[64 * XS];
    __shared__ float ldsw[128 * 64];
    int row0 = blockIdx.x * 64;
    stage_x(dyn0, ldsn, row0, kLN);
    stage_w<128>(w1, ldsw);
    int rblk = threadIdx.x >> 4, cblk = threadIdx.x & 15;
    __syncthreads();
    // emit t=0 slab
#pragma unroll
    for (int i = 0; i < 4; ++i) {
        int row = row0 + 4 * rblk + i;
        if (row < kLN) {
            float4 x0 = *reinterpret_cast<const float4*>(ldsn + (4 * rblk + i) * XS + 4 * cblk);
            *reinterpret_cast<float4*>(all_dyn + (size_t)row * 64 + 4 * cblk) = x0;
        }
    }
#pragma unroll 1
    for (int t = 1; t < kT; ++t) {
        stage_x(stat + (size_t)t * kLN * kD, ldss, row0, kLN);
        __syncthreads();
        float4 acc[4] = {};
        gemm_core(ldsn, ldsw, rblk, cblk, acc);
        gemm_core(ldss, ldsw + 64 * 64, rblk, cblk, acc);
        float4 nv[4];
#pragma unroll
        for (int i = 0; i < 4; ++i) {
            int row = row0 + 4 * rblk + i;
            int rc  = row < kLN ? row : kLN - 1;
            float tt = thre[t * kLN + rc];
            float4 xn = *reinterpret_cast<const float4*>(ldsn + (4 * rblk + i) * XS + 4 * cblk);
            nv[i].x = sigf(acc[i].x * tt + xn.x * (1.f - tt));
            nv[i].y = sigf(acc[i].y * tt + xn.y * (1.f - tt));
            nv[i].z = sigf(acc[i].z * tt + xn.z * (1.f - tt));
            nv[i].w = sigf(acc[i].w * tt + xn.w * (1.f - tt));
            if (row < kLN) {
                float4 df;
                df.x = nv[i].x - xn.x; df.y = nv[i].y - xn.y;
                df.z = nv[i].z - xn.z; df.w = nv[i].w - xn.w;
                *reinterpret_cast<float4*>(all_dyn + ((size_t)t * kLN + row) * 64 + 4 * cblk) = nv[i];
                *reinterpret_cast<float4*>(diff + ((size_t)(t - 1) * kLN + row) * 64 + 4 * cblk) = df;
                if (t == kT - 1)
                    *reinterpret_cast<float4*>(now_final + (size_t)row * 64 + 4 * cblk) = nv[i];
            }
        }
        __syncthreads();   // all reads of ldsn/ldss done before overwrite
#pragma unroll
        for (int i = 0; i < 4; ++i)
            *reinterpret_cast<float4*>(ldsn + (4 * rblk + i) * XS + 4 * cblk) = nv[i];
    }
}

// Batched over 6 chains (blockIdx.y = c). Q in-place over b1[c], XK -> b2[c].
__global__ void __launch_bounds__(256) gemm_qk(const float* __restrict__ Xdyn,
                                               const float* __restrict__ Xstat,
                                               const float* __restrict__ wq_all,
                                               const float* __restrict__ wk_all,
                                               float* __restrict__ b1,
                                               float* __restrict__ b2, int step) {
    __shared__ float ldsx[64 * XS];
    __shared__ float ldswq[64 * 64];
    __shared__ float ldswk[64 * 64];
    int c = blockIdx.y;
    int m = c / 3;
    float* b1c = b1 + (size_t)c * kBUF;
    float* b2c = b2 + (size_t)c * kBUF;
    const float* X = step ? b1c : (m == 0 ? Xdyn : Xstat);
    size_t woff = (size_t)(c * 2 + step) * kD * kD;
    int row0 = blockIdx.x * 64;
    stage_x(X, ldsx, row0, kTLN);
    stage_w<64>(wq_all + woff, ldswq);
    stage_w<64>(wk_all + woff, ldswk);
    __syncthreads();
    int rblk = threadIdx.x >> 4, cblk = threadIdx.x & 15;
    float4 aq[4] = {}, ak[4] = {};
    gemm_core2(ldsx, ldswq, ldswk, rblk, cblk, aq, ak);
#pragma unroll
    for (int i = 0; i < 4; ++i) {
        size_t row = row0 + 4 * rblk + i;
        *reinterpret_cast<float4*>(b1c + row * 64 + 4 * cblk) = aq[i];
        *reinterpret_cast<float4*>(b2c + row * 64 + 4 * cblk) = ak[i];
    }
}

// Fused score+softmax+combine+wd, batched over 6 chains, XCD-swizzled.
// wd is read straight from global in the gemm (16KB, L1-resident) so LDS is
// only the O tile -> ~2x resident waves vs staging wd to LDS.
__global__ void __launch_bounds__(256) scorewd_kernel(float* __restrict__ b1,
                                                      const float* __restrict__ b2,
                                                      const int* __restrict__ npoi,
                                                      const int* __restrict__ nroad,
                                                      const int* __restrict__ nrec,
                                                      const float* __restrict__ wd_all,
                                                      int step) {
    __shared__ float ldsx[64 * XS];
    int p   = blockIdx.y * gridDim.x + blockIdx.x;
    int xcd = p & 7;
    int gid = xcd * 375 + (p >> 3);      // 0..2999
    int c    = gid / 500;
    int tile = gid - c * 500;
    int g = c % 3;
    float* b1c = b1 + (size_t)c * kBUF;
    const float* b2c = b2 + (size_t)c * kBUF;
    const int* neigh = (g == 0) ? npoi : (g == 1) ? nroad : nrec;
    const float* gw = wd_all + (size_t)(c * 2 + step) * kD * kD;

    int lane = threadIdx.x & 63;
    int wv   = threadIdx.x >> 6;
    int sub  = lane >> 4;
    int gq   = lane & 15;
    int row0 = tile * 64;
#pragma unroll 1
    for (int pp = 0; pp < 4; ++pp) {
        int lr  = pp * 16 + wv * 4 + sub;    // local row 0..63
        int row = row0 + lr;
        int n   = row % kN;
        int slab = row - n;
        float4 q = *(reinterpret_cast<const float4*>(b1c) + (size_t)row * 16 + gq);
        const int4* nbp = reinterpret_cast<const int4*>(neigh + n * kK);
        int4 nb0 = nbp[0], nb1 = nbp[1], nb2 = nbp[2];
        int nb[12] = {nb0.x, nb0.y, nb0.z, nb0.w, nb1.x, nb1.y, nb1.z, nb1.w,
                      nb2.x, nb2.y, nb2.z, nb2.w};
        float4 kv[12];
        float sc[12];
#pragma unroll
        for (int j = 0; j < 12; ++j) {
            kv[j] = *(reinterpret_cast<const float4*>(b2c) + (size_t)(slab + nb[j]) * 16 + gq);
            sc[j] = q.x * kv[j].x + q.y * kv[j].y + q.z * kv[j].z + q.w * kv[j].w;
        }
#pragma unroll
        for (int off = 1; off < 16; off <<= 1) {
#pragma unroll
            for (int j = 0; j < 12; ++j) sc[j] += __shfl_xor(sc[j], off, 16);
        }
        float mx = sc[0];
#pragma unroll
        for (int j = 1; j < 12; ++j) mx = fmaxf(mx, sc[j]);
        float ssum = 0.f;
#pragma unroll
        for (int j = 0; j < 12; ++j) { sc[j] = __expf(sc[j] - mx); ssum += sc[j]; }
        float inv = 1.f / ssum;
        float4 o = q;
#pragma unroll
        for (int j = 0; j < 12; ++j) {
            float a = sc[j] * inv;
            o.x = fmaf(a, kv[j].x, o.x);
            o.y = fmaf(a, kv[j].y, o.y);
            o.z = fmaf(a, kv[j].z, o.z);
            o.w = fmaf(a, kv[j].w, o.w);
        }
        *reinterpret_cast<float4*>(ldsx + lr * XS + 4 * gq) = o;
    }
    __syncthreads();
    int rblk = threadIdx.x >> 4, cblk = threadIdx.x & 15;
    float4 acc[4] = {};
    gemm_core_gw(ldsx, gw, rblk, cblk, acc);
#pragma unroll
    for (int i = 0; i < 4; ++i) {
        size_t idx = ((size_t)(row0 + 4 * rblk + i)) * 64 + 4 * cblk;
        float4 y;
        y.x = sigf(acc[i].x); y.y = sigf(acc[i].y);
        y.z = sigf(acc[i].z); y.w = sigf(acc[i].w);
        *reinterpret_cast<float4*>(b1c + idx) = y;
    }
}

// LSTM with the mix fused in: per l-step, reads the 6 y-buffers, forms
// mixd/mixs on the fly. 16 lanes per (t,n) cell, width-16 shfl reduce.
__global__ void __launch_bounds__(256) lstm_kernel(const float* __restrict__ b1,
                                                   const float* __restrict__ wmix,
                                                   const float* __restrict__ cw,
                                                   const float* __restrict__ cb,
                                                   float* __restrict__ hlast) {
    int lane = threadIdx.x & 63;
    int wv   = threadIdx.x >> 6;
    int sub  = lane >> 4;
    int fq   = lane & 15;
    int cell = blockIdx.x * 16 + wv * 4 + sub;   // 0..3999
    int t = cell / kN, n = cell % kN;
    float wd_[4][4], ws_[4][4], wh[4], bb[4];
#pragma unroll
    for (int gg = 0; gg < 4; ++gg) {
#pragma unroll
        for (int k = 0; k < 4; ++k) {
            wd_[gg][k] = cw[gg * 129 + fq * 4 + k];
            ws_[gg][k] = cw[gg * 129 + 64 + fq * 4 + k];
        }
        wh[gg] = cw[gg * 129 + 128];
        bb[gg] = cb[gg];
    }
    float4 wm[6];
#pragma unroll
    for (int j = 0; j < 6; ++j)
        wm[j] = *reinterpret_cast<const float4*>(wmix + j * 64 + fq * 4);
    float h = 0.f, cc = 0.f;
#pragma unroll 1
    for (int l = 0; l < kL; ++l) {
        size_t row16 = ((size_t)(t * kL + l) * kN + n) * 16 + fq;
        float4 y[6];
#pragma unroll
        for (int j = 0; j < 6; ++j)
            y[j] = *(reinterpret_cast<const float4*>(b1) + (size_t)j * (kBUF / 4) + row16);
        float4 xd, xs;
        xd.x = sigf(y[0].x * wm[0].x + y[1].x * wm[1].x + y[2].x * wm[2].x);
        xd.y = sigf(y[0].y * wm[0].y + y[1].y * wm[1].y + y[2].y * wm[2].y);
        xd.z = sigf(y[0].z * wm[0].z + y[1].z * wm[1].z + y[2].z * wm[2].z);
        xd.w = sigf(y[0].w * wm[0].w + y[1].w * wm[1].w + y[2].w * wm[2].w);
        xs.x = sigf(y[3].x * wm[3].x + y[4].x * wm[4].x + y[5].x * wm[5].x);
        xs.y = sigf(y[3].y * wm[3].y + y[4].y * wm[4].y + y[5].y * wm[5].y);
        xs.z = sigf(y[3].z * wm[3].z + y[4].z * wm[4].z + y[5].z * wm[5].z);
        xs.w = sigf(y[3].w * wm[3].w + y[4].w * wm[4].w + y[5].w * wm[5].w);
        float gsum[4];
#pragma unroll
        for (int gg = 0; gg < 4; ++gg) {
            float v = xd.x * wd_[gg][0] + xd.y * wd_[gg][1]
                    + xd.z * wd_[gg][2] + xd.w * wd_[gg][3];
            v += xs.x * ws_[gg][0] + xs.y * ws_[gg][1]
               + xs.z * ws_[gg][2] + xs.w * ws_[gg][3];
            gsum[gg] = v;
        }
#pragma unroll
        for (int off = 1; off < 16; off <<= 1) {
#pragma unroll
            for (int gg = 0; gg < 4; ++gg) gsum[gg] += __shfl_xor(gsum[gg], off, 16);
        }
        float gi = sigf(gsum[0] + bb[0] + h * wh[0]);
        float gf = sigf(gsum[1] + bb[1] + h * wh[1]);
        float go = sigf(gsum[2] + bb[2] + h * wh[2]);
        float gg_ = tanhf(gsum[3] + bb[3] + h * wh[3]);
        cc = gf * cc + gi * gg_;
        h = go * tanhf(cc);
    }
    if (fq == 0) hlast[cell] = h;
}

// out[t,m] = sigmoid(sum_n h[t,n]*fw[m,n] + fb[m]); one wave per output.
__global__ void final_kernel(const float* __restrict__ h, const float* __restrict__ fw,
                             const float* __restrict__ fb, float* __restrict__ out) {
    int wave = threadIdx.x >> 6, lane = threadIdx.x & 63;
    int o = blockIdx.x * 4 + wave;
    int t = o / kN, m = o % kN;
    float acc = 0.f;
    for (int n = lane; n < kN; n += 64)
        acc = fmaf(h[t * kN + n], fw[(size_t)m * kN + n], acc);
#pragma unroll
    for (int off = 32; off > 0; off >>= 1) acc += __shfl_xor(acc, off);
    if (lane == 0) out[o] = sigf(acc + fb[m]);
}

extern "C" void kernel_launch(void* const* d_in, const int* in_sizes, int n_in,
                              void* d_out, int out_size, void* d_ws, size_t ws_size,
                              hipStream_t stream) {
    const float* stat   = (const float*)d_in[0];
    const float* thre   = (const float*)d_in[1];
    const float* dyn0   = (const float*)d_in[2];
    const int*   npoi   = (const int*)d_in[3];
    const int*   nroad  = (const int*)d_in[4];
    const int*   nrec   = (const int*)d_in[5];
    const float* w1     = (const float*)d_in[6];
    const float* wq_all = (const float*)d_in[7];
    const float* wk_all = (const float*)d_in[8];
    const float* wd_all = (const float*)d_in[9];
    const float* wmix   = (const float*)d_in[10];
    const float* conv_w = (const float*)d_in[11];
    const float* conv_b = (const float*)d_in[12];
    const float* fin_w  = (const float*)d_in[13];
    const float* fin_b  = (const float*)d_in[14];

    float* out       = (float*)d_out;                 // (T,N)
    float* now_final = out + kT * kN;                 // (L,N,D)
    float* diffs     = now_final + (size_t)kLN * kD;  // (T-1,L,N,D)

    float* ws      = (float*)d_ws;
    float* all_dyn = ws;                              // (T,L,N,D)
    float* b1      = ws + (size_t)kBUF;               // 6 x Q/y chain buffers
    float* b2      = ws + 7 * (size_t)kBUF;           // 6 x XK buffers
    float* hlast   = ws + 13 * (size_t)kBUF;          // (T,N)

    // ---- evolution scan: one kernel, also emits t=0 slab and now_final ----
    evo_all_kernel<<<(kLN + 63) / 64, 256, 0, stream>>>(stat, thre, dyn0,
                                                        all_dyn, diffs, now_final, w1);

    // ---- attention: 6 chains batched, 2 steps ----
    dim3 agrid(kTLN / 64, 6);
    gemm_qk<<<agrid, 256, 0, stream>>>(all_dyn, stat, wq_all, wk_all, b1, b2, 0);
    scorewd_kernel<<<agrid, 256, 0, stream>>>(b1, b2, npoi, nroad, nrec, wd_all, 0);
    gemm_qk<<<agrid, 256, 0, stream>>>(all_dyn, stat, wq_all, wk_all, b1, b2, 1);
    scorewd_kernel<<<agrid, 256, 0, stream>>>(b1, b2, npoi, nroad, nrec, wd_all, 1);

    // ---- LSTM (mix fused) over l, then final projection ----
    lstm_kernel<<<kT * kN / 16, 256, 0, stream>>>(b1, wmix, conv_w, conv_b, hlast);
    final_kernel<<<kT * kN / 4, 256, 0, stream>>>(hlast, fin_w, fin_b, out);
}